// Round 6
// baseline (197.830 us; speedup 1.0000x reference)
//
#include <hip/hip_runtime.h>

// KAN B-spline layer via MFMA, register-resident A-fragments.
// out[b,o] = sum_k basis[b,k] * W[k,o],  k = 12*feat + coeff  (K=768)
// k-map (both operands, same bijection -> HW-wiring invariant):
//   k = 192*g + 8*s + e   (g = lane>>4, s = K-step 0..23, e = frag elem 0..7)
// => lane-group g owns features 16g..16g+15; steps 3t..3t+2 <-> feats 2t,2t+1.
// Each wave: 32 rows x 64 cols, A built in registers (no LDS A), B staged in
// LDS in two 48KB halves, read as lane-contiguous ds_read_b128.
//
// ROUND 6 = MEASUREMENT ROUND: main kernel launched REPS=5 times (idempotent)
// so T_main = (dur_r6 - dur_r5) / 4. Kernel body byte-identical to round 5.

typedef short short8 __attribute__((ext_vector_type(8)));
typedef float f32x4 __attribute__((ext_vector_type(4)));
typedef unsigned u32x4 __attribute__((ext_vector_type(4)));

#define NSTEP 24
#define HSTEP 12            // steps per LDS pass
#define WAVES 8
#define THREADS (WAVES * 64)   // 512
#define RPW 32              // rows per wave (2 m-tiles)
#define RPB (WAVES * RPW)   // 256 rows per block
#define REPS 5              // main-kernel replicas for slope timing

static __device__ __forceinline__ unsigned bf16rne(float f) {
  unsigned u = __float_as_uint(f);
  return (u + 0x7FFFu + ((u >> 16) & 1u)) >> 16;   // RNE, low 16 bits valid
}

// ---- prep: pack W into B-fragments, layout [pass][ntile][sl][lane][4 dw] ----
__global__ __launch_bounds__(256) void prep_wfrag(const float* __restrict__ cp,
                                                  unsigned* __restrict__ wfrag) {
  int id = blockIdx.x * 256 + threadIdx.x;   // 0..24575 dwords
  int d  = id & 3;
  int l  = (id >> 2) & 63;
  int id2 = id >> 8;               // 0..95 = (p*4 + nt)*12 + sl
  int p   = id2 / 48;
  int rem = id2 - p * 48;
  int nt  = rem / 12;
  int sl  = rem - nt * 12;
  int s   = p * 12 + sl;
  int g   = l >> 4;
  int o   = nt * 16 + (l & 15);
  int k0  = 192 * g + 8 * s + 2 * d;
  unsigned lo = bf16rne(cp[k0 * 64 + o]);
  unsigned hi = bf16rne(cp[(k0 + 1) * 64 + o]);
  wfrag[id] = lo | (hi << 16);
}

struct Pack6 { unsigned w0, w1, w2, w3, w4, w5; };   // dense-12 bf16 (coeffs 2q,2q+1)

static __device__ __forceinline__ Pack6 eval_pack(float xi) {
  xi = fminf(fmaxf(xi, 0.0f), 1.0f);
  float t9 = xi * 9.0f;
  int jj = (int)t9;
  float validf = (jj <= 8) ? 1.0f : 0.0f;   // x==1 -> zero row (ref semantics)
  jj = (jj > 8) ? 8 : jj;
  float fj = (float)jj;
  float u  = t9 - fj;
  float omu = 1.0f - u;
  float c1  = fminf(fj, 1.0f);
  float c2  = fminf(fj, 2.0f);
  float rdj = 9.0f - fj;
  float d2p = fminf(rdj, 2.0f);
  float d3p = fminf(rdj, 3.0f);
  float invA = (jj == 0) ? 1.0f : 0.5f;
  float invB = (jj == 8) ? 1.0f : 0.5f;
  float invC = (jj == 0) ? 1.0f : ((jj == 1) ? 0.5f : (1.0f / 3.0f));
  float invD = (jj == 0 || jj == 8) ? 0.5f : (1.0f / 3.0f);
  float invE = (jj >= 7) ? ((jj == 8) ? 1.0f : 0.5f) : (1.0f / 3.0f);
  float xkm1 = u + c1, xkm2 = u + c2;
  float k2x = d2p - u, k3x = d3p - u;
  float t0 = omu * invA;
  float A0 = omu * t0;
  float s1 = xkm1 * t0;
  float t1 = u * invB;
  float A1 = fmaf(k2x, t1, s1);
  float A2 = u * t1;
  float u0 = A0 * invC;
  float B0 = omu * u0;
  float s2 = xkm2 * u0;
  float u1 = A1 * invD;
  float B1 = fmaf(k2x, u1, s2);
  float s3 = xkm1 * u1;
  float u2 = A2 * invE;
  float B2 = fmaf(k3x, u2, s3);
  float B3 = u * u2;
  B0 *= validf; B1 *= validf; B2 *= validf; B3 *= validf;

  unsigned b0 = bf16rne(B0), b1 = bf16rne(B1), b2 = bf16rne(B2), b3 = bf16rne(B3);
  unsigned p01 = b0 | (b1 << 16);
  unsigned p23 = b2 | (b3 << 16);
  unsigned O0 = p01 << 16;
  unsigned O1 = (p01 >> 16) | (p23 << 16);
  unsigned O2 = p23 >> 16;
  int e2 = jj >> 1;
  bool odd = (jj & 1) != 0;
#define VE(q) ((q == e2) ? p01 : ((q == e2 + 1) ? p23 : 0u))
#define VO(q) ((q == e2) ? O0 : ((q == e2 + 1) ? O1 : ((q == e2 + 2) ? O2 : 0u)))
  Pack6 r;
  r.w0 = odd ? VO(0) : VE(0);
  r.w1 = odd ? VO(1) : VE(1);
  r.w2 = odd ? VO(2) : VE(2);
  r.w3 = odd ? VO(3) : VE(3);
  r.w4 = odd ? VO(4) : VE(4);
  r.w5 = odd ? VO(5) : VE(5);
#undef VE
#undef VO
  return r;
}

__global__ __launch_bounds__(THREADS) void kan_mfma(const float* __restrict__ x,
                                                    const unsigned* __restrict__ wfrag,
                                                    float* __restrict__ out) {
  __shared__ u32x4 ldsB[4 * HSTEP * 64];   // 48 KB per pass
  const int tid  = threadIdx.x;
  const int lane = tid & 63;
  const int w    = tid >> 6;
  const int m = lane & 15, g = lane >> 4;
  const long row0 = ((long)blockIdx.x * WAVES + w) * RPW;

  // ---- x for this lane: its 2 rows x its 16 feature columns (contiguous) ----
  float xr0[16], xr1[16];
  {
    const float4* p0 = (const float4*)(x + (row0 + m) * 64 + g * 16);
    const float4* p1 = (const float4*)(x + (row0 + 16 + m) * 64 + g * 16);
    #pragma unroll
    for (int q = 0; q < 4; ++q) {
      float4 v = p0[q];
      xr0[4 * q] = v.x; xr0[4 * q + 1] = v.y; xr0[4 * q + 2] = v.z; xr0[4 * q + 3] = v.w;
    }
    #pragma unroll
    for (int q = 0; q < 4; ++q) {
      float4 v = p1[q];
      xr1[4 * q] = v.x; xr1[4 * q + 1] = v.y; xr1[4 * q + 2] = v.z; xr1[4 * q + 3] = v.w;
    }
  }

  f32x4 acc[2][4];
  #pragma unroll
  for (int mt = 0; mt < 2; ++mt)
    #pragma unroll
    for (int nt = 0; nt < 4; ++nt)
      acc[mt][nt] = f32x4{0.0f, 0.0f, 0.0f, 0.0f};

  const u32x4* wsrc = (const u32x4*)wfrag;

  #pragma unroll
  for (int p = 0; p < 2; ++p) {
    if (p) __syncthreads();               // all waves done reading pass-0 B
    #pragma unroll
    for (int q = 0; q < (4 * HSTEP * 64) / THREADS; ++q)     // 6 x u32x4 each
      ldsB[q * THREADS + tid] = wsrc[p * 3072 + q * THREADS + tid];
    __syncthreads();

    #pragma unroll
    for (int tl = 0; tl < 4; ++tl) {
      const int t = p * 4 + tl;
      // 4 independent evals: feats 16g+2t, 16g+2t+1 for both m-tiles
      Pack6 aA = eval_pack(xr0[2 * t]);
      Pack6 aB = eval_pack(xr0[2 * t + 1]);
      Pack6 bA = eval_pack(xr1[2 * t]);
      Pack6 bB = eval_pack(xr1[2 * t + 1]);
      #pragma unroll
      for (int sub = 0; sub < 3; ++sub) {
        u32x4 qa, qb;
        if (sub == 0) {
          qa[0] = aA.w0; qa[1] = aA.w1; qa[2] = aA.w2; qa[3] = aA.w3;
          qb[0] = bA.w0; qb[1] = bA.w1; qb[2] = bA.w2; qb[3] = bA.w3;
        } else if (sub == 1) {
          qa[0] = aA.w4; qa[1] = aA.w5; qa[2] = aB.w0; qa[3] = aB.w1;
          qb[0] = bA.w4; qb[1] = bA.w5; qb[2] = bB.w0; qb[3] = bB.w1;
        } else {
          qa[0] = aB.w2; qa[1] = aB.w3; qa[2] = aB.w4; qa[3] = aB.w5;
          qb[0] = bB.w2; qb[1] = bB.w3; qb[2] = bB.w4; qb[3] = bB.w5;
        }
        short8 A0 = __builtin_bit_cast(short8, qa);
        short8 A1 = __builtin_bit_cast(short8, qb);
        const int sl = 3 * tl + sub;
        #pragma unroll
        for (int nt = 0; nt < 4; ++nt) {
          u32x4 bq = ldsB[(nt * HSTEP + sl) * 64 + lane];  // lane-contiguous b128
          short8 B = __builtin_bit_cast(short8, bq);
          acc[0][nt] = __builtin_amdgcn_mfma_f32_16x16x32_bf16(A0, B, acc[0][nt], 0, 0, 0);
          acc[1][nt] = __builtin_amdgcn_mfma_f32_16x16x32_bf16(A1, B, acc[1][nt], 0, 0, 0);
        }
      }
    }
  }

  // ---- stores: 16 contiguous dwords per 16-lane group ----
  #pragma unroll
  for (int mt = 0; mt < 2; ++mt)
    #pragma unroll
    for (int nt = 0; nt < 4; ++nt)
      #pragma unroll
      for (int j = 0; j < 4; ++j)
        out[(row0 + mt * 16 + g * 4 + j) * 64 + nt * 16 + m] = acc[mt][nt][j];
}

extern "C" void kernel_launch(void* const* d_in, const int* in_sizes, int n_in,
                              void* d_out, int out_size, void* d_ws, size_t ws_size,
                              hipStream_t stream) {
  const float* x  = (const float*)d_in[0];
  const float* cp = (const float*)d_in[1];
  float* out = (float*)d_out;
  unsigned* wfrag = (unsigned*)d_ws;       // 24576 dwords = 96 KB

  hipLaunchKernelGGL(prep_wfrag, dim3(96), dim3(256), 0, stream, cp, wfrag);
  const int rows = in_sizes[0] / 64;       // 65536
  // REPS identical idempotent launches: dur_us slope isolates T_main.
  for (int rep = 0; rep < REPS; ++rep)
    hipLaunchKernelGGL(kan_mfma, dim3(rows / RPB), dim3(THREADS), 0, stream,
                       x, wfrag, out);
}

// Round 7
// 87.540 us; speedup vs baseline: 2.2599x; 2.2599x over previous
//
#include <hip/hip_runtime.h>

// KAN B-spline layer via MFMA, register-resident A-fragments, B converted
// in-block (no prep kernel, d_ws unused).
// out[b,o] = sum_k basis[b,k] * W[k,o],  k = 12*feat + coeff  (K=768)
// k-map (both operands, same bijection -> HW-wiring invariant):
//   k = 192*g + 8*s + e   (g = lane>>4, s = K-step 0..23, e = frag elem 0..7)
// => lane-group g owns features 16g..16g+15; steps 3t..3t+2 <-> feats 2t,2t+1.
// 16 waves/block (1024 thr) x 16 rows/wave = 256 rows/block, grid 256 ->
// 1 block/CU, 4 waves/SIMD (latency hiding). B staged in 2 x 48KB LDS passes,
// converted from cp on the fly, read as lane-contiguous ds_read_b128.

typedef short short8 __attribute__((ext_vector_type(8)));
typedef float f32x4 __attribute__((ext_vector_type(4)));
typedef unsigned u32x4 __attribute__((ext_vector_type(4)));

#define WAVES 16
#define THREADS (WAVES * 64)   // 1024
#define RPW 16                 // rows per wave (1 m-tile)
#define RPB (WAVES * RPW)      // 256 rows per block
#define HSTEP 12               // K-steps per LDS pass

static __device__ __forceinline__ unsigned bf16rne(float f) {
  unsigned u = __float_as_uint(f);
  return (u + 0x7FFFu + ((u >> 16) & 1u)) >> 16;   // RNE, low 16 bits valid
}

struct Pack6 { unsigned w0, w1, w2, w3, w4, w5; };   // dense-12 bf16 (coeffs 2q,2q+1)

static __device__ __forceinline__ Pack6 eval_pack(float xi) {
  xi = fminf(fmaxf(xi, 0.0f), 1.0f);
  float t9 = xi * 9.0f;
  int jj = (int)t9;
  float validf = (jj <= 8) ? 1.0f : 0.0f;   // x==1 -> zero row (ref semantics)
  jj = (jj > 8) ? 8 : jj;
  float fj = (float)jj;
  float u  = t9 - fj;
  float omu = 1.0f - u;
  float c1  = fminf(fj, 1.0f);
  float c2  = fminf(fj, 2.0f);
  float rdj = 9.0f - fj;
  float d2p = fminf(rdj, 2.0f);
  float d3p = fminf(rdj, 3.0f);
  float invA = (jj == 0) ? 1.0f : 0.5f;
  float invB = (jj == 8) ? 1.0f : 0.5f;
  float invC = (jj == 0) ? 1.0f : ((jj == 1) ? 0.5f : (1.0f / 3.0f));
  float invD = (jj == 0 || jj == 8) ? 0.5f : (1.0f / 3.0f);
  float invE = (jj >= 7) ? ((jj == 8) ? 1.0f : 0.5f) : (1.0f / 3.0f);
  float xkm1 = u + c1, xkm2 = u + c2;
  float k2x = d2p - u, k3x = d3p - u;
  float t0 = omu * invA;
  float A0 = omu * t0;
  float s1 = xkm1 * t0;
  float t1 = u * invB;
  float A1 = fmaf(k2x, t1, s1);
  float A2 = u * t1;
  float u0 = A0 * invC;
  float B0 = omu * u0;
  float s2 = xkm2 * u0;
  float u1 = A1 * invD;
  float B1 = fmaf(k2x, u1, s2);
  float s3 = xkm1 * u1;
  float u2 = A2 * invE;
  float B2 = fmaf(k3x, u2, s3);
  float B3 = u * u2;
  B0 *= validf; B1 *= validf; B2 *= validf; B3 *= validf;

  unsigned b0 = bf16rne(B0), b1 = bf16rne(B1), b2 = bf16rne(B2), b3 = bf16rne(B3);
  unsigned p01 = b0 | (b1 << 16);
  unsigned p23 = b2 | (b3 << 16);
  unsigned O0 = p01 << 16;
  unsigned O1 = (p01 >> 16) | (p23 << 16);
  unsigned O2 = p23 >> 16;
  int e2 = jj >> 1;
  bool odd = (jj & 1) != 0;
#define VE(q) ((q == e2) ? p01 : ((q == e2 + 1) ? p23 : 0u))
#define VO(q) ((q == e2) ? O0 : ((q == e2 + 1) ? O1 : ((q == e2 + 2) ? O2 : 0u)))
  Pack6 r;
  r.w0 = odd ? VO(0) : VE(0);
  r.w1 = odd ? VO(1) : VE(1);
  r.w2 = odd ? VO(2) : VE(2);
  r.w3 = odd ? VO(3) : VE(3);
  r.w4 = odd ? VO(4) : VE(4);
  r.w5 = odd ? VO(5) : VE(5);
#undef VE
#undef VO
  return r;
}

__global__ __launch_bounds__(THREADS, 4) void kan_mfma(const float* __restrict__ x,
                                                       const float* __restrict__ cp,
                                                       float* __restrict__ out) {
  __shared__ u32x4 ldsB[4 * HSTEP * 64];   // 48 KB per pass
  const int tid  = threadIdx.x;
  const int lane = tid & 63;
  const int w    = tid >> 6;
  const int m = lane & 15, g = lane >> 4;
  const long row0 = (long)blockIdx.x * RPB + w * RPW;

  // ---- x for this lane: its row x its 16 feature columns (issued first:
  //      HBM latency hides under the B-conversion phase) ----
  float xr[16];
  {
    const float4* p0 = (const float4*)(x + (row0 + m) * 64 + g * 16);
    #pragma unroll
    for (int q = 0; q < 4; ++q) {
      float4 v = p0[q];
      xr[4 * q] = v.x; xr[4 * q + 1] = v.y; xr[4 * q + 2] = v.z; xr[4 * q + 3] = v.w;
    }
  }

  f32x4 acc[4];
  #pragma unroll
  for (int nt = 0; nt < 4; ++nt) acc[nt] = f32x4{0.0f, 0.0f, 0.0f, 0.0f};

  #pragma unroll
  for (int p = 0; p < 2; ++p) {
    if (p) __syncthreads();               // all waves done reading pass-0 B

    // ---- convert + stage this pass's B-fragments: cp (L2-resident) -> LDS ----
    #pragma unroll
    for (int q = 0; q < (4 * HSTEP * 64) / THREADS; ++q) {   // 3 x u32x4 each
      int sidx = q * THREADS + tid;       // dest slot
      int l2   = sidx & 63;
      int idx2 = sidx >> 6;               // 0..47 = nt*12 + sl
      int nt   = idx2 / HSTEP;
      int sl   = idx2 - nt * HSTEP;
      int gg   = l2 >> 4;
      int o    = nt * 16 + (l2 & 15);
      int kb   = 192 * gg + 8 * (p * HSTEP + sl);
      const float* src = cp + o;
      u32x4 v;
      #pragma unroll
      for (int d = 0; d < 4; ++d) {
        unsigned lo = bf16rne(src[(kb + 2 * d) * 64]);
        unsigned hi = bf16rne(src[(kb + 2 * d + 1) * 64]);
        v[d] = lo | (hi << 16);
      }
      ldsB[sidx] = v;
    }
    __syncthreads();

    // ---- 4 feature-pairs per pass: eval in regs, 3 MFMA steps each ----
    #pragma unroll
    for (int tl = 0; tl < 4; ++tl) {
      const int t = p * 4 + tl;
      Pack6 aA = eval_pack(xr[2 * t]);
      Pack6 aB = eval_pack(xr[2 * t + 1]);
      #pragma unroll
      for (int sub = 0; sub < 3; ++sub) {
        u32x4 qa;
        if (sub == 0)      { qa[0] = aA.w0; qa[1] = aA.w1; qa[2] = aA.w2; qa[3] = aA.w3; }
        else if (sub == 1) { qa[0] = aA.w4; qa[1] = aA.w5; qa[2] = aB.w0; qa[3] = aB.w1; }
        else               { qa[0] = aB.w2; qa[1] = aB.w3; qa[2] = aB.w4; qa[3] = aB.w5; }
        short8 A = __builtin_bit_cast(short8, qa);
        const int sl = 3 * tl + sub;
        #pragma unroll
        for (int nt = 0; nt < 4; ++nt) {
          u32x4 bq = ldsB[(nt * HSTEP + sl) * 64 + lane];  // lane-contiguous b128
          short8 B = __builtin_bit_cast(short8, bq);
          acc[nt] = __builtin_amdgcn_mfma_f32_16x16x32_bf16(A, B, acc[nt], 0, 0, 0);
        }
      }
    }
  }

  // ---- stores: 16 contiguous dwords per 16-lane group ----
  #pragma unroll
  for (int nt = 0; nt < 4; ++nt)
    #pragma unroll
    for (int j = 0; j < 4; ++j)
      out[(row0 + g * 4 + j) * 64 + nt * 16 + m] = acc[nt][j];
}

extern "C" void kernel_launch(void* const* d_in, const int* in_sizes, int n_in,
                              void* d_out, int out_size, void* d_ws, size_t ws_size,
                              hipStream_t stream) {
  const float* x  = (const float*)d_in[0];
  const float* cp = (const float*)d_in[1];
  float* out = (float*)d_out;
  const int rows = in_sizes[0] / 64;       // 65536
  hipLaunchKernelGGL(kan_mfma, dim3(rows / RPB), dim3(THREADS), 0, stream,
                     x, cp, out);
}